// Round 7
// baseline (32.561 us; speedup 1.0000x reference)
//
#include <hip/hip_runtime.h>

// CapsulePooling2D: x (32,64,64,256) f32 -> out (32,32,32,256) f32.
// One 64-lane wave per (batch, 2x2 block); lane owns 4 channels (float4).
//
// Gram reformulation: all cross-lane reductions factor through the 4x4
// Gram matrix G[m][k] = x_m . x_k (over 256 channels):
//   a      = 0.25 * sum_m n_m x_m
//   a.a    = (1/16) sum_{m,k} n_m n_k G[m][k]
//   x_k.a  = 0.25  * sum_m   n_m G[k][m]
// So G is reduced ONCE (10 parallel width-64 butterflies); the 3-step
// iteration is pure wave-uniform VALU (no shuffles), and the output a is
// formed once at the end with the step-3 weights. Live regs ~34 (x:16,
// G:10, s/n:8) -> fits 64-VGPR budget -> 8 waves/SIMD occupancy.

static constexpr float EPS = 1e-7f;

typedef float f32x4 __attribute__((ext_vector_type(4)));  // native vec for nt-store

__device__ __forceinline__ float dot4(const float4& u, const float4& v) {
    return u.x * v.x + u.y * v.y + u.z * v.z + u.w * v.w;
}

__global__ __launch_bounds__(256, 8) void capsule_pool_kernel(
    const float* __restrict__ x, float* __restrict__ out)
{
    constexpr int H = 64, W = 64, C = 256;
    constexpr int HB = H / 2, WB = W / 2;   // 32 x 32 pooled grid

    const int lane   = threadIdx.x & 63;
    const int waveId = threadIdx.x >> 6;
    const int blk = blockIdx.x * 4 + waveId;   // global 2x2-block id, 0..32767

    const int j = blk & (WB - 1);
    const int i = (blk >> 5) & (HB - 1);
    const int b = blk >> 10;

    const size_t rowStride = (size_t)W * C;
    const float* p = x + ((size_t)b * H + 2 * i) * rowStride
                       + (size_t)(2 * j) * C + 4 * lane;

    // 4 pixels x 4 channels/lane
    const float4 x0 = *(const float4*)(p);
    const float4 x1 = *(const float4*)(p + C);
    const float4 x2 = *(const float4*)(p + rowStride);
    const float4 x3 = *(const float4*)(p + rowStride + C);

    // per-lane Gram partials (10 unique entries)
    float g00 = dot4(x0, x0), g01 = dot4(x0, x1), g02 = dot4(x0, x2), g03 = dot4(x0, x3);
    float g11 = dot4(x1, x1), g12 = dot4(x1, x2), g13 = dot4(x1, x3);
    float g22 = dot4(x2, x2), g23 = dot4(x2, x3), g33 = dot4(x3, x3);

    // allreduce over the 64 lanes (10 parallel butterflies)
    #pragma unroll
    for (int off = 1; off < 64; off <<= 1) {
        g00 += __shfl_xor(g00, off, 64);
        g01 += __shfl_xor(g01, off, 64);
        g02 += __shfl_xor(g02, off, 64);
        g03 += __shfl_xor(g03, off, 64);
        g11 += __shfl_xor(g11, off, 64);
        g12 += __shfl_xor(g12, off, 64);
        g13 += __shfl_xor(g13, off, 64);
        g22 += __shfl_xor(g22, off, 64);
        g23 += __shfl_xor(g23, off, 64);
        g33 += __shfl_xor(g33, off, 64);
    }

    // 3-step iteration: pure wave-uniform scalar math on G
    float s0 = 0.f, s1 = 0.f, s2 = 0.f, s3 = 0.f;
    float n0 = 1.f, n1 = 1.f, n2 = 1.f, n3 = 1.f;
    #pragma unroll
    for (int step = 0; step < 3; ++step) {
        if (step > 0) {
            // normalize_pool_map: within-block softmax-like weights, T=2
            const float m = fmaxf(fmaxf(s0, s1), fmaxf(s2, s3));
            const float e0 = expf((s0 - m) * 0.5f);
            const float e1 = expf((s1 - m) * 0.5f);
            const float e2 = expf((s2 - m) * 0.5f);
            const float e3 = expf((s3 - m) * 0.5f);
            const float inv = 1.f / (0.25f * (e0 + e1 + e2 + e3) + EPS);
            n0 = e0 * inv; n1 = e1 * inv; n2 = e2 * inv; n3 = e3 * inv;
        }
        if (step < 2) {   // step 3's score update is dead code in the reference
            const float q0 = n0 * g00 + n1 * g01 + n2 * g02 + n3 * g03;
            const float q1 = n0 * g01 + n1 * g11 + n2 * g12 + n3 * g13;
            const float q2 = n0 * g02 + n1 * g12 + n2 * g22 + n3 * g23;
            const float q3 = n0 * g03 + n1 * g13 + n2 * g23 + n3 * g33;
            const float aa2 = 0.0625f * (n0 * q0 + n1 * q1 + n2 * q2 + n3 * q3);
            const float scale = 1.f / (1.f + sqrtf(aa2) + EPS);
            s0 += 0.25f * q0 * scale;
            s1 += 0.25f * q1 * scale;
            s2 += 0.25f * q2 * scale;
            s3 += 0.25f * q3 * scale;
        }
    }

    // output: a = avg-pool of step-3 weighted fm (this lane's 4 channels)
    f32x4 a;
    a.x = 0.25f * (n0 * x0.x + n1 * x1.x + n2 * x2.x + n3 * x3.x);
    a.y = 0.25f * (n0 * x0.y + n1 * x1.y + n2 * x2.y + n3 * x3.y);
    a.z = 0.25f * (n0 * x0.z + n1 * x1.z + n2 * x2.z + n3 * x3.z);
    a.w = 0.25f * (n0 * x0.w + n1 * x1.w + n2 * x2.w + n3 * x3.w);

    float* o = out + (((size_t)b * HB + i) * WB + j) * C + 4 * lane;
    __builtin_nontemporal_store(a, (f32x4*)o);
}

extern "C" void kernel_launch(void* const* d_in, const int* in_sizes, int n_in,
                              void* d_out, int out_size, void* d_ws, size_t ws_size,
                              hipStream_t stream) {
    const float* x = (const float*)d_in[0];
    float* out = (float*)d_out;
    // 32768 blocks, 4 waves (one block each) per 256-thread workgroup
    capsule_pool_kernel<<<8192, 256, 0, stream>>>(x, out);
}